// Round 6
// baseline (4827.755 us; speedup 1.0000x reference)
//
#include <hip/hip_runtime.h>
#include <math.h>

#define TSTEPS 48
#define NCELL 32
#define ND 224
#define NBLK (NCELL + ND)

// ---------------- ws float offsets ----------------
#define OFF_W0T   0            // [2 hh][128 k4][512 gc] float4 (Wih0 re-layout)
#define OFF_W1T   524288       // [2][64][512] float4 (Wih1)
#define OFF_WH0T  786432       // [2][64][512] float4 (Whh0)
#define OFF_WH1T  1048576      // [2][64][512] float4 (Whh1)
#define OFF_BS0   1310720      // [2 hh][512 gc]
#define OFF_BS1   1311744
#define OFF_HINIT 1312768      // [64][256]
#define OFF_CINIT 1329152
#define OFF_H0BUF 1345536      // [64][256]
#define OFF_H1BUF 1361920
#define OFF_FLOAT_END 1378304
// then: key2 u64[64][256] (131072 B), flags u32[12288] (49152 B)

#define FSTR 32
#define FL_H0F   0       // 32
#define FL_H1C   1024    // 32
#define FL_H1ALL 2048    // 32 (unused since r5: D polls H1C directly)
#define FL_DFLAG 3072    // 224
#define FL_DMIR  10240   // 32
#define FL_TOK   11264   // 32
#define NFLAGU32 12288

typedef float f4v __attribute__((ext_vector_type(4)));

// ---- coherent accessors ----
__device__ __forceinline__ unsigned ld_cohu(const unsigned* p) {
  return __hip_atomic_load((unsigned*)p, __ATOMIC_RELAXED, __HIP_MEMORY_SCOPE_AGENT);
}
__device__ __forceinline__ void st_cohu(unsigned* p, unsigned v) {
  __hip_atomic_store(p, v, __ATOMIC_RELAXED, __HIP_MEMORY_SCOPE_AGENT);
}
__device__ __forceinline__ unsigned long long ld_coh64(const unsigned long long* p) {
  return __hip_atomic_load((unsigned long long*)p, __ATOMIC_RELAXED, __HIP_MEMORY_SCOPE_AGENT);
}
__device__ __forceinline__ void st_coh64(unsigned long long* p, unsigned long long v) {
  __hip_atomic_store(p, v, __ATOMIC_RELAXED, __HIP_MEMORY_SCOPE_AGENT);
}
// 16B coherent load (bypass L0+L2 -> IC), blocking
__device__ __forceinline__ float4 ldg_coh_f4(const float4* p) {
  f4v r;
  asm volatile("global_load_dwordx4 %0, %1, off sc0 sc1\n\ts_waitcnt vmcnt(0)"
               : "=v"(r) : "v"(p) : "memory");
  return make_float4(r.x, r.y, r.z, r.w);
}
// 4 x 16B coherent loads in flight, one wait
__device__ __forceinline__ void ldg_coh_f4x4(const float4* p0, const float4* p1,
                                             const float4* p2, const float4* p3,
                                             float4& a, float4& b, float4& c, float4& d) {
  f4v ra, rb, rc, rd;
  asm volatile(
      "global_load_dwordx4 %0, %4, off sc0 sc1\n\t"
      "global_load_dwordx4 %1, %5, off sc0 sc1\n\t"
      "global_load_dwordx4 %2, %6, off sc0 sc1\n\t"
      "global_load_dwordx4 %3, %7, off sc0 sc1\n\t"
      "s_waitcnt vmcnt(0)"
      : "=&v"(ra), "=&v"(rb), "=&v"(rc), "=&v"(rd)
      : "v"(p0), "v"(p1), "v"(p2), "v"(p3) : "memory");
  a = make_float4(ra.x, ra.y, ra.z, ra.w);
  b = make_float4(rb.x, rb.y, rb.z, rb.w);
  c = make_float4(rc.x, rc.y, rc.z, rc.w);
  d = make_float4(rd.x, rd.y, rd.z, rd.w);
}
// 16B coherent write-through store (fire and forget; drain_vm before flag post)
__device__ __forceinline__ void stg_coh_f4(float4* p, float4 v) {
  f4v t = {v.x, v.y, v.z, v.w};
  asm volatile("global_store_dwordx4 %0, %1, off sc0 sc1" :: "v"(p), "v"(t) : "memory");
}
__device__ __forceinline__ void drain_vm() {
  asm volatile("s_waitcnt vmcnt(0)" ::: "memory");
}
// non-temporal 16B load (streaming; don't pollute L2 — protects cell weights in L2)
__device__ __forceinline__ float4 ldnt_f4(const float4* p) {
  f4v v = __builtin_nontemporal_load((const f4v*)p);
  return make_float4(v.x, v.y, v.z, v.w);
}
__device__ __forceinline__ float sigf(float x) { return 1.0f / (1.0f + expf(-x)); }
__device__ __forceinline__ unsigned long long u64max(unsigned long long a, unsigned long long b) {
  return a > b ? a : b;
}
__device__ __forceinline__ unsigned long long wmax64(unsigned long long k) {
#pragma unroll
  for (int off = 1; off < 64; off <<= 1) {
    unsigned long long o = __shfl_xor(k, off, 64);
    k = u64max(k, o);
  }
  return k;
}
__device__ __forceinline__ unsigned long long packkey(float lg, int v) {
  unsigned u = __float_as_uint(lg);
  u = (u & 0x80000000u) ? ~u : (u | 0x80000000u);
  return ((unsigned long long)u << 32) | (unsigned)(~(unsigned)v);
}
__device__ __forceinline__ float4 f4add(float4 a, float4 b) {
  return make_float4(a.x + b.x, a.y + b.y, a.z + b.z, a.w + b.w);
}

// ---------------- init kernels ----------------
__global__ void lstm_init_kernel(const float* enc, const float* Wh, const float* bh,
                                 const float* Wc, const float* bc,
                                 const float* bih0, const float* bhh0,
                                 const float* bih1, const float* bhh1,
                                 float* ws, unsigned long long* key2, unsigned* flags) {
  const int tid = threadIdx.x, blk = blockIdx.x;
  if (blk < 64) {
    __shared__ float el[256];
    el[tid] = enc[blk * 256 + tid];
    __syncthreads();
    const float4* el4 = (const float4*)el;
    const float4* wh4 = (const float4*)(Wh + tid * 256);
    const float4* wc4 = (const float4*)(Wc + tid * 256);
    float ah = bh[tid], ac = bc[tid];
#pragma unroll 4
    for (int f = 0; f < 64; ++f) {
      float4 x = el4[f], a = wh4[f], b = wc4[f];
      ah = fmaf(a.x, x.x, fmaf(a.y, x.y, fmaf(a.z, x.z, fmaf(a.w, x.w, ah))));
      ac = fmaf(b.x, x.x, fmaf(b.y, x.y, fmaf(b.z, x.z, fmaf(b.w, x.w, ac))));
    }
    ws[OFF_HINIT + blk * 256 + tid] = ah;
    ws[OFF_CINIT + blk * 256 + tid] = ac;
  } else if (blk == 64) {
    for (int g = tid; g < 1024; g += 256) {
      int hh = g >> 9, gc = g & 511;
      int row = (gc >> 7) * 256 + hh * 128 + (gc & 127);
      ws[OFF_BS0 + g] = bih0[row] + bhh0[row];
      ws[OFF_BS1 + g] = bih1[row] + bhh1[row];
    }
  } else {
    const int base = (blk - 65) * 256 + tid;  // 15 blocks, stride 3840
    for (int i = base; i < 64 * 256; i += 15 * 256) key2[i] = 0ull;
    for (int i = base; i < NFLAGU32; i += 15 * 256) flags[i] = 0u;
  }
}

// re-layout the 4 gate-weight matrices into [hh][k4][512 gc] float4
__global__ void lstm_relayout_kernel(const float* Wih0, const float* Whh0,
                                     const float* Wih1, const float* Whh1, float* ws) {
  const int gid = blockIdx.x * 256 + threadIdx.x;
  const int gstr = 256 * 256;
  const float* srcs[4] = {Wih0, Wih1, Whh0, Whh1};
  const int dsts[4] = {OFF_W0T, OFF_W1T, OFF_WH0T, OFF_WH1T};
  const int k4tot[4] = {128, 64, 64, 64};
  for (int s = 0; s < 4; ++s) {
    const int n = 2 * k4tot[s] * 512;
    float4* dst = (float4*)(ws + dsts[s]);
    const float4* src = (const float4*)srcs[s];
    for (int e = gid; e < n; e += gstr) {
      int hh = e / (k4tot[s] * 512);
      int r = e - hh * k4tot[s] * 512;
      int k4 = r / 512, gc = r - k4 * 512;
      int row = (gc >> 7) * 256 + hh * 128 + (gc & 127);
      dst[e] = src[(size_t)row * k4tot[s] + k4];
    }
  }
}

// ---------------- decode: shared-memory layouts ----------------
struct CellSm {
  float x[4 * 512];
  float4 part[1024];
  float4 r0res[512];
  float4 r1res[512];
  float h0[4 * 256];
  float h1[4 * 256];
  float c0[4 * 128];
  float c1[4 * 128];
  int tok[4];
  unsigned fm[32];
  unsigned long long fred[16];
  int done4;
  int alldone;
};
struct DSm {
  float w[16 * 144 * 4];        // [k4][144 rows][4]
  float h[64 * 68];             // [b][68] (padded, 16B-aligned rows)
  unsigned long long kr[64];    // [batch] folded keys
};
union Smem { CellSm c; DSm d; };

// GEMV half: thread (gc = tid&511, kh = tid>>9) accumulates its K-half for 4 batches.
template <int K4H>
__device__ __forceinline__ void gemv_half(const float4* __restrict__ W,
                                          const float* __restrict__ xl, int xstride,
                                          float4* __restrict__ part, int tid) {
  const int kh = tid >> 9;
  float a0 = 0.f, a1 = 0.f, a2 = 0.f, a3 = 0.f;
  const float4* wp = W + (size_t)(kh * K4H) * 512 + (tid & 511);
  const float* x0 = xl + kh * K4H * 4;
#pragma unroll 8
  for (int i = 0; i < K4H; ++i) {
    float4 w = wp[(size_t)i * 512];
    float4 xa = *(const float4*)(x0 + i * 4);
    float4 xb = *(const float4*)(x0 + xstride + i * 4);
    float4 xc = *(const float4*)(x0 + 2 * xstride + i * 4);
    float4 xd = *(const float4*)(x0 + 3 * xstride + i * 4);
    a0 = fmaf(w.x, xa.x, fmaf(w.y, xa.y, fmaf(w.z, xa.z, fmaf(w.w, xa.w, a0))));
    a1 = fmaf(w.x, xb.x, fmaf(w.y, xb.y, fmaf(w.z, xb.z, fmaf(w.w, xb.w, a1))));
    a2 = fmaf(w.x, xc.x, fmaf(w.y, xc.y, fmaf(w.z, xc.z, fmaf(w.w, xc.w, a2))));
    a3 = fmaf(w.x, xd.x, fmaf(w.y, xd.y, fmaf(w.z, xd.z, fmaf(w.w, xd.w, a3))));
  }
  part[tid] = make_float4(a0, a1, a2, a3);
}

__device__ __forceinline__ void cellfold(const float4* part, const float4* rres,
                                         const float* bs, float* cst, float* hst,
                                         int hh, int tid) {
  if (tid < 512) {
    int jj = tid & 127, b = tid >> 7;
    float g[4];
#pragma unroll
    for (int q = 0; q < 4; ++q) {
      int gc = q * 128 + jj;
      g[q] = ((const float*)&part[gc])[b] + ((const float*)&part[512 + gc])[b] +
             ((const float*)&rres[gc])[b] + bs[gc];
    }
    float c = cst[b * 128 + jj];
    float cn = sigf(g[1]) * c + sigf(g[0]) * tanhf(g[2]);
    float hn = sigf(g[3]) * tanhf(cn);
    cst[b * 128 + jj] = cn;
    hst[b * 256 + hh * 128 + jj] = hn;
  }
}

__global__ __launch_bounds__(1024, 4) void lstm_decode_kernel(
    const float* __restrict__ emb, const float* __restrict__ Wout,
    const float* __restrict__ bout, const int* __restrict__ sosp,
    const int* __restrict__ eosp, float* __restrict__ ws,
    unsigned long long* __restrict__ key2, unsigned* __restrict__ flags,
    int* __restrict__ out) {
  const int tid = threadIdx.x;
  const int blk = blockIdx.x;
  __shared__ Smem sm;
  const int eos = *eosp;
  const int sos = *sosp;
  float4* h0b4 = (float4*)(ws + OFF_H0BUF);
  float4* h1b4 = (float4*)(ws + OFF_H1BUF);

  if (blk < NCELL) {
    // ======================= CELL block =======================
    const int bg = blk >> 1, hh = blk & 1, ph = 1 - hh;
    const float4* W0 = (const float4*)(ws + OFF_W0T) + (size_t)hh * 128 * 512;
    const float4* W1 = (const float4*)(ws + OFF_W1T) + (size_t)hh * 64 * 512;
    const float4* WH0 = (const float4*)(ws + OFF_WH0T) + (size_t)hh * 64 * 512;
    const float4* WH1 = (const float4*)(ws + OFF_WH1T) + (size_t)hh * 64 * 512;
    const float* bs0 = ws + OFF_BS0 + hh * 512;
    const float* bs1 = ws + OFF_BS1 + hh * 512;

    // t=0 state seed
    {
      int b = tid >> 8, k = tid & 255;
      float hv = ws[OFF_HINIT + (bg * 4 + b) * 256 + k];
      sm.c.h0[b * 256 + k] = hv;
      sm.c.h1[b * 256 + k] = hv;
    }
    if (tid < 512) {
      int b = tid >> 7, jj = tid & 127;
      float cv = ws[OFF_CINIT + (bg * 4 + b) * 256 + hh * 128 + jj];
      sm.c.c0[b * 128 + jj] = cv;
      sm.c.c1[b * 128 + jj] = cv;
    }
    if (tid < 4) sm.c.tok[tid] = sos;
    if (tid == 0) { sm.c.done4 = 0; sm.c.alldone = 0; }
    __syncthreads();
    // seed R0res/R1res from init states
    gemv_half<32>(WH0, sm.c.h0, 256, sm.c.part, tid);
    __syncthreads();
    if (tid < 512) sm.c.r0res[tid] = f4add(sm.c.part[tid], sm.c.part[512 + tid]);
    __syncthreads();
    gemv_half<32>(WH1, sm.c.h1, 256, sm.c.part, tid);
    __syncthreads();
    if (tid < 512) sm.c.r1res[tid] = f4add(sm.c.part[tid], sm.c.part[512 + tid]);
    __syncthreads();

    for (int t = 0; t < TSTEPS; ++t) {
      const unsigned T = (unsigned)(t + 1);
      // ---- E = Wih0(half) @ emb[tok] ----
      if (tid < 512) {
        int b = tid >> 7, j = tid & 127;
        ((float4*)sm.c.x)[b * 128 + j] = ((const float4*)emb)[(size_t)sm.c.tok[b] * 128 + j];
      }
      __syncthreads();
      gemv_half<64>(W0, sm.c.x, 512, sm.c.part, tid);
      __syncthreads();
      cellfold(sm.c.part, sm.c.r0res, bs0, sm.c.c0, sm.c.h0, hh, tid);
      __syncthreads();
      // post own h0 half, exchange with partner
      if (tid < 128) {
        int b = tid >> 5, j = tid & 31;
        float4 v = *(float4*)&sm.c.h0[b * 256 + hh * 128 + j * 4];
        stg_coh_f4(h0b4 + (bg * 4 + b) * 64 + hh * 32 + j, v);
      }
      drain_vm();
      __syncthreads();
      if (tid == 0) {
        st_cohu(flags + FL_H0F + blk * FSTR, T);
        while (ld_cohu(flags + FL_H0F + (blk ^ 1) * FSTR) < T) __builtin_amdgcn_s_sleep(1);
      }
      __syncthreads();
      if (tid < 128) {
        int b = tid >> 5, j = tid & 31;
        float4 v = ldg_coh_f4(h0b4 + (bg * 4 + b) * 64 + ph * 32 + j);
        *(float4*)&sm.c.h0[b * 256 + ph * 128 + j * 4] = v;
      }
      __syncthreads();
      // ---- G1 = Wih1(half) @ h0 ----
      gemv_half<32>(W1, sm.c.h0, 256, sm.c.part, tid);
      __syncthreads();
      cellfold(sm.c.part, sm.c.r1res, bs1, sm.c.c1, sm.c.h1, hh, tid);
      __syncthreads();
      // post h1 half + flag; D blocks observe the 32 H1C flags directly (no relay).
      if (tid < 128) {
        int b = tid >> 5, j = tid & 31;
        float4 v = *(float4*)&sm.c.h1[b * 256 + hh * 128 + j * 4];
        stg_coh_f4(h1b4 + (bg * 4 + b) * 64 + hh * 32 + j, v);
      }
      drain_vm();
      __syncthreads();
      if (tid == 0) {
        st_cohu(flags + FL_H1C + blk * FSTR, T);
        // only the partner's half is needed locally (for R1)
        while (ld_cohu(flags + FL_H1C + (blk ^ 1) * FSTR) < T) __builtin_amdgcn_s_sleep(1);
      }
      __syncthreads();
      // read partner h1 half (for R1)
      if (tid < 128) {
        int b = tid >> 5, j = tid & 31;
        float4 v = ldg_coh_f4(h1b4 + (bg * 4 + b) * 64 + ph * 32 + j);
        *(float4*)&sm.c.h1[b * 256 + ph * 128 + j * 4] = v;
      }
      __syncthreads();
      // ---- off-path: masks from step t-1 (for alldone) ----
      if (t > 0) {
        if (tid < 64) {
          unsigned tgt = (unsigned)t << 8;
          unsigned got = tgt;
          for (;;) {
            if (tid < 32) got = ld_cohu(flags + FL_TOK + tid * FSTR);
            if (__all((int)(got >= tgt))) break;
            __builtin_amdgcn_s_sleep(2);
          }
          if (tid < 32) sm.c.fm[tid] = got & 0xFFu;
        }
        __syncthreads();
        if (tid < 64) {
          int ok = 1;
          if (tid < 32) ok = (sm.c.fm[tid] == 0xFu);
          int all = __all(ok);
          if (tid == 0) sm.c.alldone = all;
        }
        __syncthreads();
      }
      // ---- off-path: R0/R1 for next step ----
      gemv_half<32>(WH0, sm.c.h0, 256, sm.c.part, tid);
      __syncthreads();
      if (tid < 512) sm.c.r0res[tid] = f4add(sm.c.part[tid], sm.c.part[512 + tid]);
      __syncthreads();
      gemv_half<32>(WH1, sm.c.h1, 256, sm.c.part, tid);
      __syncthreads();
      if (tid < 512) sm.c.r1res[tid] = f4add(sm.c.part[tid], sm.c.part[512 + tid]);
      __syncthreads();
      // ---- D-completion mirror ----
      if (tid < 64) {
        unsigned v = T;
        for (;;) {
          if (tid < 7) v = ld_cohu(flags + FL_DFLAG + (blk * 7 + tid) * FSTR);
          if (__all((int)(v >= T))) break;
          __builtin_amdgcn_s_sleep(4);
        }
      }
      __syncthreads();
      if (tid == 0) st_cohu(flags + FL_DMIR + blk * FSTR, T);
      if (tid < 64) {
        unsigned v = T;
        for (;;) {
          if (tid < 32) v = ld_cohu(flags + FL_DMIR + tid * FSTR);
          if (__all((int)(v >= T))) break;
          __builtin_amdgcn_s_sleep(2);
        }
      }
      __syncthreads();
      // ---- argmax fold for own 4 batches ----
      {
        int bb = tid >> 8, i = tid & 255;
        unsigned long long k = ld_coh64(key2 + (size_t)(bg * 4 + bb) * 256 + i);
        k = wmax64(k);
        if ((tid & 63) == 0) sm.c.fred[tid >> 6] = k;
      }
      __syncthreads();
      if (tid < 4) {
        int bb = tid;
        unsigned long long m = u64max(u64max(sm.c.fred[bb * 4], sm.c.fred[bb * 4 + 1]),
                                      u64max(sm.c.fred[bb * 4 + 2], sm.c.fred[bb * 4 + 3]));
        int v = (int)(~(unsigned)m);
        int outv = sm.c.alldone ? 0 : v;
        out[(bg * 4 + bb) * TSTEPS + t] = outv;
        int nd = ((sm.c.done4 >> bb) & 1) | (outv == eos ? 1 : 0);
        sm.c.tok[bb] = outv;
        sm.c.fm[bb] = (unsigned)nd;
      }
      __syncthreads();
      if (tid == 0) {
        int mask = (int)(sm.c.fm[0] | (sm.c.fm[1] << 1) | (sm.c.fm[2] << 2) | (sm.c.fm[3] << 3));
        sm.c.done4 = mask;
        if (t < TSTEPS - 1)
          st_cohu(flags + FL_TOK + blk * FSTR, ((unsigned)(t + 1) << 8) | (unsigned)mask);
      }
      __syncthreads();
    }
  } else {
    // ======================= D (logits) block =======================
    // Tile: thread = (v = tid&31 row-slot, bp = tid>>5 batch-pair).
    // Rows {v, 32+v, 64+v, 96+v} + epi row 128+v (v<nep); batches {2bp, 2bp+1}.
    // Per wave per k4: 4 half-wide w + 1 masked epi-w + 2 paired h = 7 LDS
    // issues (vs 11 before). Key fold: 5-step half-wave shuffle (vs 48 issues).
    const int d = blk - NCELL;
    const int r0 = (d * 32000) / ND, r1 = ((d + 1) * 32000) / ND;
    const int rows = r1 - r0, nep = rows - 128;  // 14 or 15
    const int v = tid & 31, bp = tid >> 5;
    const float4* Wout4 = (const float4*)Wout;
    const int nq = 144 * 16;

    float bbm[4];
#pragma unroll
    for (int rs = 0; rs < 4; ++rs) bbm[rs] = bout[r0 + rs * 32 + v];
    const float bbE = (v < nep) ? bout[r0 + 128 + v] : 0.f;

    for (int t = 0; t < TSTEPS; ++t) {
      const unsigned T = (unsigned)(t + 1);
      // prefetch kc=0 Wout chunk (token-independent)
      float4 wpre[3];
#pragma unroll
      for (int p = 0; p < 3; ++p) {
        int e = tid + p * 1024;
        if (e < nq) {
          int j = e / 144, r = e - j * 144;
          int rc = r0 + r; if (rc > 31999) rc = 31999;
          wpre[p] = ldnt_f4(Wout4 + (size_t)rc * 64 + j);
        } else wpre[p] = make_float4(0.f, 0.f, 0.f, 0.f);
      }
      // EARLY-STAGE kc0 w into LDS (token-independent; prior step's end-barrier
      // ordered all reads of sm.d.w before this write) — overlaps the h1 wait.
#pragma unroll
      for (int p = 0; p < 3; ++p) {
        int e = tid + p * 1024;
        if (e < nq) {
          int j = e / 144, r = e - j * 144;
          *(float4*)&sm.d.w[(j * 144 + r) * 4] = wpre[p];
        }
      }
      // wait h1 ready: wave0 polls all 32 H1C flags directly (no cell relay)
      if (tid < 64) {
        unsigned hv = T;
        for (;;) {
          if (tid < 32) hv = ld_cohu(flags + FL_H1C + tid * FSTR);
          if (__all((int)(hv >= T))) break;
          __builtin_amdgcn_s_sleep(4);
        }
      }
      __syncthreads();
      // read full h1 into registers (4 x 16B batched coherent loads)
      float4 hpre[4];
      {
        int b = tid >> 4, j = tid & 15;
        const float4* hp = (const float4*)h1b4 + (size_t)b * 64 + j;
        ldg_coh_f4x4(hp, hp + 16, hp + 32, hp + 48, hpre[0], hpre[1], hpre[2], hpre[3]);
      }
      float accA[4], accB[4];
      float eaA = 0.f, eaB = 0.f;
#pragma unroll
      for (int i = 0; i < 4; ++i) { accA[i] = 0.f; accB[i] = 0.f; }

      // kc loop MUST stay fully unrolled: hpre[kc] must be statically indexed
      // (rolled loop -> scratch; that was R4's 2.3GB WRITE_SIZE regression).
#pragma unroll
      for (int kc = 0; kc < 4; ++kc) {
        if (kc > 0) {
          __syncthreads();
#pragma unroll
          for (int p = 0; p < 3; ++p) {
            int e = tid + p * 1024;
            if (e < nq) {
              int j = e / 144, r = e - j * 144;
              *(float4*)&sm.d.w[(j * 144 + r) * 4] = wpre[p];
            }
          }
        }
        {
          int b = tid >> 4, j = tid & 15;
          *(float4*)&sm.d.h[b * 68 + j * 4] = hpre[kc];
        }
        __syncthreads();
        if (kc < 3) {
#pragma unroll
          for (int p = 0; p < 3; ++p) {
            int e = tid + p * 1024;
            if (e < nq) {
              int j = e / 144, r = e - j * 144;
              int rc = r0 + r; if (rc > 31999) rc = 31999;
              wpre[p] = ldnt_f4(Wout4 + (size_t)rc * 64 + (kc + 1) * 16 + j);
            }
          }
        }
        // main: 4 rows x 2 batches (+ epi row x 2 batches)
#pragma unroll 4
        for (int k4 = 0; k4 < 16; ++k4) {
          const float* wb = &sm.d.w[(k4 * 144) * 4];
          float4 w0 = *(const float4*)&wb[v * 4];
          float4 w1 = *(const float4*)&wb[(32 + v) * 4];
          float4 w2 = *(const float4*)&wb[(64 + v) * 4];
          float4 w3 = *(const float4*)&wb[(96 + v) * 4];
          float4 hA = *(const float4*)&sm.d.h[(2 * bp) * 68 + k4 * 4];
          float4 hB = *(const float4*)&sm.d.h[(2 * bp + 1) * 68 + k4 * 4];
          accA[0] = fmaf(w0.x, hA.x, fmaf(w0.y, hA.y, fmaf(w0.z, hA.z, fmaf(w0.w, hA.w, accA[0]))));
          accB[0] = fmaf(w0.x, hB.x, fmaf(w0.y, hB.y, fmaf(w0.z, hB.z, fmaf(w0.w, hB.w, accB[0]))));
          accA[1] = fmaf(w1.x, hA.x, fmaf(w1.y, hA.y, fmaf(w1.z, hA.z, fmaf(w1.w, hA.w, accA[1]))));
          accB[1] = fmaf(w1.x, hB.x, fmaf(w1.y, hB.y, fmaf(w1.z, hB.z, fmaf(w1.w, hB.w, accB[1]))));
          accA[2] = fmaf(w2.x, hA.x, fmaf(w2.y, hA.y, fmaf(w2.z, hA.z, fmaf(w2.w, hA.w, accA[2]))));
          accB[2] = fmaf(w2.x, hB.x, fmaf(w2.y, hB.y, fmaf(w2.z, hB.z, fmaf(w2.w, hB.w, accB[2]))));
          accA[3] = fmaf(w3.x, hA.x, fmaf(w3.y, hA.y, fmaf(w3.z, hA.z, fmaf(w3.w, hA.w, accA[3]))));
          accB[3] = fmaf(w3.x, hB.x, fmaf(w3.y, hB.y, fmaf(w3.z, hB.z, fmaf(w3.w, hB.w, accB[3]))));
          if (v < nep) {
            float4 wE = *(const float4*)&wb[(128 + v) * 4];
            eaA = fmaf(wE.x, hA.x, fmaf(wE.y, hA.y, fmaf(wE.z, hA.z, fmaf(wE.w, hA.w, eaA))));
            eaB = fmaf(wE.x, hB.x, fmaf(wE.y, hB.y, fmaf(wE.z, hB.z, fmaf(wE.w, hB.w, eaB))));
          }
        }
      }
      // ---- keys: per-thread fold over 4(+1) rows, then 5-step half-wave reduce ----
      unsigned long long kA = packkey(accA[0] + bbm[0], r0 + v);
      kA = u64max(kA, packkey(accA[1] + bbm[1], r0 + 32 + v));
      kA = u64max(kA, packkey(accA[2] + bbm[2], r0 + 64 + v));
      kA = u64max(kA, packkey(accA[3] + bbm[3], r0 + 96 + v));
      unsigned long long kB = packkey(accB[0] + bbm[0], r0 + v);
      kB = u64max(kB, packkey(accB[1] + bbm[1], r0 + 32 + v));
      kB = u64max(kB, packkey(accB[2] + bbm[2], r0 + 64 + v));
      kB = u64max(kB, packkey(accB[3] + bbm[3], r0 + 96 + v));
      if (v < nep) {
        kA = u64max(kA, packkey(eaA + bbE, r0 + 128 + v));
        kB = u64max(kB, packkey(eaB + bbE, r0 + 128 + v));
      }
      // offsets 1..16: lanes stay within their 32-lane half (no batch mixing)
#pragma unroll
      for (int off = 1; off < 32; off <<= 1) {
        kA = u64max(kA, __shfl_xor(kA, off, 64));
        kB = u64max(kB, __shfl_xor(kB, off, 64));
      }
      if ((tid & 31) == 0) {
        sm.d.kr[2 * bp] = kA;
        sm.d.kr[2 * bp + 1] = kB;
      }
      __syncthreads();
      if (tid < 64) st_coh64(key2 + (size_t)tid * 256 + d, sm.d.kr[tid]);
      drain_vm();
      __syncthreads();
      if (tid == 0) st_cohu(flags + FL_DFLAG + d * FSTR, T);
    }
  }
}

extern "C" void kernel_launch(void* const* d_in, const int* in_sizes, int n_in,
                              void* d_out, int out_size, void* d_ws, size_t ws_size,
                              hipStream_t stream) {
  const float* enc  = (const float*)d_in[0];
  const float* emb  = (const float*)d_in[1];
  const float* Wh   = (const float*)d_in[2];
  const float* bh   = (const float*)d_in[3];
  const float* Wc   = (const float*)d_in[4];
  const float* bc   = (const float*)d_in[5];
  const float* Wih0 = (const float*)d_in[6];
  const float* Whh0 = (const float*)d_in[7];
  const float* bih0 = (const float*)d_in[8];
  const float* bhh0 = (const float*)d_in[9];
  const float* Wih1 = (const float*)d_in[10];
  const float* Whh1 = (const float*)d_in[11];
  const float* bih1 = (const float*)d_in[12];
  const float* bhh1 = (const float*)d_in[13];
  const float* Wout = (const float*)d_in[14];
  const float* bout = (const float*)d_in[15];
  const int* sosp   = (const int*)d_in[16];
  const int* eosp   = (const int*)d_in[17];

  float* ws = (float*)d_ws;
  char* base = (char*)d_ws + (size_t)OFF_FLOAT_END * 4;
  unsigned long long* key2 = (unsigned long long*)base;            // 131072 B
  unsigned* flags          = (unsigned*)(base + 131072);           // 49152 B
  int* out = (int*)d_out;

  lstm_init_kernel<<<80, 256, 0, stream>>>(enc, Wh, bh, Wc, bc, bih0, bhh0,
                                           bih1, bhh1, ws, key2, flags);
  lstm_relayout_kernel<<<256, 256, 0, stream>>>(Wih0, Whh0, Wih1, Whh1, ws);
  lstm_decode_kernel<<<NBLK, 1024, 0, stream>>>(emb, Wout, bout, sosp, eosp,
                                                ws, key2, flags, out);
}

// Round 7
// 4820.202 us; speedup vs baseline: 1.0016x; 1.0016x over previous
//
#include <hip/hip_runtime.h>
#include <math.h>

#define TSTEPS 48
#define NCELL 32
#define ND 224
#define NBLK (NCELL + ND)

// ---------------- ws float offsets ----------------
#define OFF_W0T   0            // [2 hh][128 k4][512 gc] float4 (Wih0 re-layout)
#define OFF_W1T   524288       // [2][64][512] float4 (Wih1)
#define OFF_WH0T  786432       // [2][64][512] float4 (Whh0)
#define OFF_WH1T  1048576      // [2][64][512] float4 (Whh1)
#define OFF_BS0   1310720      // [2 hh][512 gc]
#define OFF_BS1   1311744
#define OFF_HINIT 1312768      // [64][256]
#define OFF_CINIT 1329152
#define OFF_H0BUF 1345536      // [64][256]
#define OFF_H1BUF 1361920
#define OFF_FLOAT_END 1378304
// then: key2 u64[64][256] (131072 B), flags u32[12288] (49152 B)

#define FSTR 32
#define FL_H0F   0       // 32
#define FL_H1C   1024    // 32
#define FL_H1ALL 2048    // 32 (unused since r5: D polls H1C directly)
#define FL_DFLAG 3072    // 224
#define FL_DMIR  10240   // 32
#define FL_TOK   11264   // 32
#define NFLAGU32 12288

typedef float f4v __attribute__((ext_vector_type(4)));

// ---- coherent accessors ----
__device__ __forceinline__ unsigned ld_cohu(const unsigned* p) {
  return __hip_atomic_load((unsigned*)p, __ATOMIC_RELAXED, __HIP_MEMORY_SCOPE_AGENT);
}
__device__ __forceinline__ void st_cohu(unsigned* p, unsigned v) {
  __hip_atomic_store(p, v, __ATOMIC_RELAXED, __HIP_MEMORY_SCOPE_AGENT);
}
__device__ __forceinline__ unsigned long long ld_coh64(const unsigned long long* p) {
  return __hip_atomic_load((unsigned long long*)p, __ATOMIC_RELAXED, __HIP_MEMORY_SCOPE_AGENT);
}
__device__ __forceinline__ void st_coh64(unsigned long long* p, unsigned long long v) {
  __hip_atomic_store(p, v, __ATOMIC_RELAXED, __HIP_MEMORY_SCOPE_AGENT);
}
// 16B coherent load (bypass L0+L2 -> IC), blocking
__device__ __forceinline__ float4 ldg_coh_f4(const float4* p) {
  f4v r;
  asm volatile("global_load_dwordx4 %0, %1, off sc0 sc1\n\ts_waitcnt vmcnt(0)"
               : "=v"(r) : "v"(p) : "memory");
  return make_float4(r.x, r.y, r.z, r.w);
}
// 4 x 16B coherent loads in flight, one wait
__device__ __forceinline__ void ldg_coh_f4x4(const float4* p0, const float4* p1,
                                             const float4* p2, const float4* p3,
                                             float4& a, float4& b, float4& c, float4& d) {
  f4v ra, rb, rc, rd;
  asm volatile(
      "global_load_dwordx4 %0, %4, off sc0 sc1\n\t"
      "global_load_dwordx4 %1, %5, off sc0 sc1\n\t"
      "global_load_dwordx4 %2, %6, off sc0 sc1\n\t"
      "global_load_dwordx4 %3, %7, off sc0 sc1\n\t"
      "s_waitcnt vmcnt(0)"
      : "=&v"(ra), "=&v"(rb), "=&v"(rc), "=&v"(rd)
      : "v"(p0), "v"(p1), "v"(p2), "v"(p3) : "memory");
  a = make_float4(ra.x, ra.y, ra.z, ra.w);
  b = make_float4(rb.x, rb.y, rb.z, rb.w);
  c = make_float4(rc.x, rc.y, rc.z, rc.w);
  d = make_float4(rd.x, rd.y, rd.z, rd.w);
}
// 16B coherent write-through store (fire and forget; drain_vm before flag post)
__device__ __forceinline__ void stg_coh_f4(float4* p, float4 v) {
  f4v t = {v.x, v.y, v.z, v.w};
  asm volatile("global_store_dwordx4 %0, %1, off sc0 sc1" :: "v"(p), "v"(t) : "memory");
}
__device__ __forceinline__ void drain_vm() {
  asm volatile("s_waitcnt vmcnt(0)" ::: "memory");
}
// non-temporal 16B load (streaming; don't pollute L2 — protects cell weights in L2)
__device__ __forceinline__ float4 ldnt_f4(const float4* p) {
  f4v v = __builtin_nontemporal_load((const f4v*)p);
  return make_float4(v.x, v.y, v.z, v.w);
}
__device__ __forceinline__ float sigf(float x) { return 1.0f / (1.0f + expf(-x)); }
__device__ __forceinline__ unsigned long long u64max(unsigned long long a, unsigned long long b) {
  return a > b ? a : b;
}
__device__ __forceinline__ unsigned long long wmax64(unsigned long long k) {
#pragma unroll
  for (int off = 1; off < 64; off <<= 1) {
    unsigned long long o = __shfl_xor(k, off, 64);
    k = u64max(k, o);
  }
  return k;
}
__device__ __forceinline__ unsigned long long packkey(float lg, int v) {
  unsigned u = __float_as_uint(lg);
  u = (u & 0x80000000u) ? ~u : (u | 0x80000000u);
  return ((unsigned long long)u << 32) | (unsigned)(~(unsigned)v);
}
__device__ __forceinline__ float4 f4add(float4 a, float4 b) {
  return make_float4(a.x + b.x, a.y + b.y, a.z + b.z, a.w + b.w);
}

// ---------------- init kernels ----------------
__global__ void lstm_init_kernel(const float* enc, const float* Wh, const float* bh,
                                 const float* Wc, const float* bc,
                                 const float* bih0, const float* bhh0,
                                 const float* bih1, const float* bhh1,
                                 float* ws, unsigned long long* key2, unsigned* flags) {
  const int tid = threadIdx.x, blk = blockIdx.x;
  if (blk < 64) {
    __shared__ float el[256];
    el[tid] = enc[blk * 256 + tid];
    __syncthreads();
    const float4* el4 = (const float4*)el;
    const float4* wh4 = (const float4*)(Wh + tid * 256);
    const float4* wc4 = (const float4*)(Wc + tid * 256);
    float ah = bh[tid], ac = bc[tid];
#pragma unroll 4
    for (int f = 0; f < 64; ++f) {
      float4 x = el4[f], a = wh4[f], b = wc4[f];
      ah = fmaf(a.x, x.x, fmaf(a.y, x.y, fmaf(a.z, x.z, fmaf(a.w, x.w, ah))));
      ac = fmaf(b.x, x.x, fmaf(b.y, x.y, fmaf(b.z, x.z, fmaf(b.w, x.w, ac))));
    }
    ws[OFF_HINIT + blk * 256 + tid] = ah;
    ws[OFF_CINIT + blk * 256 + tid] = ac;
  } else if (blk == 64) {
    for (int g = tid; g < 1024; g += 256) {
      int hh = g >> 9, gc = g & 511;
      int row = (gc >> 7) * 256 + hh * 128 + (gc & 127);
      ws[OFF_BS0 + g] = bih0[row] + bhh0[row];
      ws[OFF_BS1 + g] = bih1[row] + bhh1[row];
    }
  } else {
    const int base = (blk - 65) * 256 + tid;  // 15 blocks, stride 3840
    for (int i = base; i < 64 * 256; i += 15 * 256) key2[i] = 0ull;
    for (int i = base; i < NFLAGU32; i += 15 * 256) flags[i] = 0u;
  }
}

// re-layout the 4 gate-weight matrices into [hh][k4][512 gc] float4
__global__ void lstm_relayout_kernel(const float* Wih0, const float* Whh0,
                                     const float* Wih1, const float* Whh1, float* ws) {
  const int gid = blockIdx.x * 256 + threadIdx.x;
  const int gstr = 256 * 256;
  const float* srcs[4] = {Wih0, Wih1, Whh0, Whh1};
  const int dsts[4] = {OFF_W0T, OFF_W1T, OFF_WH0T, OFF_WH1T};
  const int k4tot[4] = {128, 64, 64, 64};
  for (int s = 0; s < 4; ++s) {
    const int n = 2 * k4tot[s] * 512;
    float4* dst = (float4*)(ws + dsts[s]);
    const float4* src = (const float4*)srcs[s];
    for (int e = gid; e < n; e += gstr) {
      int hh = e / (k4tot[s] * 512);
      int r = e - hh * k4tot[s] * 512;
      int k4 = r / 512, gc = r - k4 * 512;
      int row = (gc >> 7) * 256 + hh * 128 + (gc & 127);
      dst[e] = src[(size_t)row * k4tot[s] + k4];
    }
  }
}

// ---------------- decode: shared-memory layouts ----------------
struct CellSm {
  float x[4 * 512];
  float4 part[1024];
  float4 r0res[512];
  float4 r1res[512];
  float h0[4 * 256];
  float h1[4 * 256];
  float c0[4 * 128];
  float c1[4 * 128];
  int tok[4];
  unsigned fm[32];
  unsigned long long fred[16];
  int done4;
  int alldone;
};
struct DSm {
  float w[16 * 144 * 4];        // [k4][144 rows][4]
  float h[64 * 68];             // [b][68] (padded, 16B-aligned rows)
  unsigned long long kr[64];    // [batch] folded keys
};
union Smem { CellSm c; DSm d; };

// GEMV half: thread (gc = tid&511, kh = tid>>9) accumulates its K-half for 4 batches.
template <int K4H>
__device__ __forceinline__ void gemv_half(const float4* __restrict__ W,
                                          const float* __restrict__ xl, int xstride,
                                          float4* __restrict__ part, int tid) {
  const int kh = tid >> 9;
  float a0 = 0.f, a1 = 0.f, a2 = 0.f, a3 = 0.f;
  const float4* wp = W + (size_t)(kh * K4H) * 512 + (tid & 511);
  const float* x0 = xl + kh * K4H * 4;
#pragma unroll 8
  for (int i = 0; i < K4H; ++i) {
    float4 w = wp[(size_t)i * 512];
    float4 xa = *(const float4*)(x0 + i * 4);
    float4 xb = *(const float4*)(x0 + xstride + i * 4);
    float4 xc = *(const float4*)(x0 + 2 * xstride + i * 4);
    float4 xd = *(const float4*)(x0 + 3 * xstride + i * 4);
    a0 = fmaf(w.x, xa.x, fmaf(w.y, xa.y, fmaf(w.z, xa.z, fmaf(w.w, xa.w, a0))));
    a1 = fmaf(w.x, xb.x, fmaf(w.y, xb.y, fmaf(w.z, xb.z, fmaf(w.w, xb.w, a1))));
    a2 = fmaf(w.x, xc.x, fmaf(w.y, xc.y, fmaf(w.z, xc.z, fmaf(w.w, xc.w, a2))));
    a3 = fmaf(w.x, xd.x, fmaf(w.y, xd.y, fmaf(w.z, xd.z, fmaf(w.w, xd.w, a3))));
  }
  part[tid] = make_float4(a0, a1, a2, a3);
}

__device__ __forceinline__ void cellfold(const float4* part, const float4* rres,
                                         const float* bs, float* cst, float* hst,
                                         int hh, int tid) {
  if (tid < 512) {
    int jj = tid & 127, b = tid >> 7;
    float g[4];
#pragma unroll
    for (int q = 0; q < 4; ++q) {
      int gc = q * 128 + jj;
      g[q] = ((const float*)&part[gc])[b] + ((const float*)&part[512 + gc])[b] +
             ((const float*)&rres[gc])[b] + bs[gc];
    }
    float c = cst[b * 128 + jj];
    float cn = sigf(g[1]) * c + sigf(g[0]) * tanhf(g[2]);
    float hn = sigf(g[3]) * tanhf(cn);
    cst[b * 128 + jj] = cn;
    hst[b * 256 + hh * 128 + jj] = hn;
  }
}

// waves_per_eu(4,4): grid is exactly 1 block/CU (256 blocks, 1024 thr) ->
// pin the compiler to that occupancy so the VGPR budget is 128, not the
// 64-VGPR cap it picks when it speculatively targets 2 blocks/CU.
// (r4/r6 spilled 1.3-2.3 GB to scratch under the 64-reg cap.)
__global__ __launch_bounds__(1024)
__attribute__((amdgpu_waves_per_eu(4, 4))) void lstm_decode_kernel(
    const float* __restrict__ emb, const float* __restrict__ Wout,
    const float* __restrict__ bout, const int* __restrict__ sosp,
    const int* __restrict__ eosp, float* __restrict__ ws,
    unsigned long long* __restrict__ key2, unsigned* __restrict__ flags,
    int* __restrict__ out) {
  const int tid = threadIdx.x;
  const int blk = blockIdx.x;
  __shared__ Smem sm;
  const int eos = *eosp;
  const int sos = *sosp;
  float4* h0b4 = (float4*)(ws + OFF_H0BUF);
  float4* h1b4 = (float4*)(ws + OFF_H1BUF);

  if (blk < NCELL) {
    // ======================= CELL block =======================
    const int bg = blk >> 1, hh = blk & 1, ph = 1 - hh;
    const float4* W0 = (const float4*)(ws + OFF_W0T) + (size_t)hh * 128 * 512;
    const float4* W1 = (const float4*)(ws + OFF_W1T) + (size_t)hh * 64 * 512;
    const float4* WH0 = (const float4*)(ws + OFF_WH0T) + (size_t)hh * 64 * 512;
    const float4* WH1 = (const float4*)(ws + OFF_WH1T) + (size_t)hh * 64 * 512;
    const float* bs0 = ws + OFF_BS0 + hh * 512;
    const float* bs1 = ws + OFF_BS1 + hh * 512;

    // t=0 state seed
    {
      int b = tid >> 8, k = tid & 255;
      float hv = ws[OFF_HINIT + (bg * 4 + b) * 256 + k];
      sm.c.h0[b * 256 + k] = hv;
      sm.c.h1[b * 256 + k] = hv;
    }
    if (tid < 512) {
      int b = tid >> 7, jj = tid & 127;
      float cv = ws[OFF_CINIT + (bg * 4 + b) * 256 + hh * 128 + jj];
      sm.c.c0[b * 128 + jj] = cv;
      sm.c.c1[b * 128 + jj] = cv;
    }
    if (tid < 4) sm.c.tok[tid] = sos;
    if (tid == 0) { sm.c.done4 = 0; sm.c.alldone = 0; }
    __syncthreads();
    // seed R0res/R1res from init states
    gemv_half<32>(WH0, sm.c.h0, 256, sm.c.part, tid);
    __syncthreads();
    if (tid < 512) sm.c.r0res[tid] = f4add(sm.c.part[tid], sm.c.part[512 + tid]);
    __syncthreads();
    gemv_half<32>(WH1, sm.c.h1, 256, sm.c.part, tid);
    __syncthreads();
    if (tid < 512) sm.c.r1res[tid] = f4add(sm.c.part[tid], sm.c.part[512 + tid]);
    __syncthreads();

    for (int t = 0; t < TSTEPS; ++t) {
      const unsigned T = (unsigned)(t + 1);
      // ---- E = Wih0(half) @ emb[tok] ----
      if (tid < 512) {
        int b = tid >> 7, j = tid & 127;
        ((float4*)sm.c.x)[b * 128 + j] = ((const float4*)emb)[(size_t)sm.c.tok[b] * 128 + j];
      }
      __syncthreads();
      gemv_half<64>(W0, sm.c.x, 512, sm.c.part, tid);
      __syncthreads();
      cellfold(sm.c.part, sm.c.r0res, bs0, sm.c.c0, sm.c.h0, hh, tid);
      __syncthreads();
      // post own h0 half, exchange with partner
      if (tid < 128) {
        int b = tid >> 5, j = tid & 31;
        float4 v = *(float4*)&sm.c.h0[b * 256 + hh * 128 + j * 4];
        stg_coh_f4(h0b4 + (bg * 4 + b) * 64 + hh * 32 + j, v);
      }
      drain_vm();
      __syncthreads();
      if (tid == 0) {
        st_cohu(flags + FL_H0F + blk * FSTR, T);
        while (ld_cohu(flags + FL_H0F + (blk ^ 1) * FSTR) < T) __builtin_amdgcn_s_sleep(1);
      }
      __syncthreads();
      if (tid < 128) {
        int b = tid >> 5, j = tid & 31;
        float4 v = ldg_coh_f4(h0b4 + (bg * 4 + b) * 64 + ph * 32 + j);
        *(float4*)&sm.c.h0[b * 256 + ph * 128 + j * 4] = v;
      }
      __syncthreads();
      // ---- G1 = Wih1(half) @ h0 ----
      gemv_half<32>(W1, sm.c.h0, 256, sm.c.part, tid);
      __syncthreads();
      cellfold(sm.c.part, sm.c.r1res, bs1, sm.c.c1, sm.c.h1, hh, tid);
      __syncthreads();
      // post h1 half + flag; D blocks observe the 32 H1C flags directly (no relay).
      if (tid < 128) {
        int b = tid >> 5, j = tid & 31;
        float4 v = *(float4*)&sm.c.h1[b * 256 + hh * 128 + j * 4];
        stg_coh_f4(h1b4 + (bg * 4 + b) * 64 + hh * 32 + j, v);
      }
      drain_vm();
      __syncthreads();
      if (tid == 0) {
        st_cohu(flags + FL_H1C + blk * FSTR, T);
        // only the partner's half is needed locally (for R1)
        while (ld_cohu(flags + FL_H1C + (blk ^ 1) * FSTR) < T) __builtin_amdgcn_s_sleep(1);
      }
      __syncthreads();
      // read partner h1 half (for R1)
      if (tid < 128) {
        int b = tid >> 5, j = tid & 31;
        float4 v = ldg_coh_f4(h1b4 + (bg * 4 + b) * 64 + ph * 32 + j);
        *(float4*)&sm.c.h1[b * 256 + ph * 128 + j * 4] = v;
      }
      __syncthreads();
      // ---- off-path: masks from step t-1 (for alldone) ----
      if (t > 0) {
        if (tid < 64) {
          unsigned tgt = (unsigned)t << 8;
          unsigned got = tgt;
          for (;;) {
            if (tid < 32) got = ld_cohu(flags + FL_TOK + tid * FSTR);
            if (__all((int)(got >= tgt))) break;
            __builtin_amdgcn_s_sleep(2);
          }
          if (tid < 32) sm.c.fm[tid] = got & 0xFFu;
        }
        __syncthreads();
        if (tid < 64) {
          int ok = 1;
          if (tid < 32) ok = (sm.c.fm[tid] == 0xFu);
          int all = __all(ok);
          if (tid == 0) sm.c.alldone = all;
        }
        __syncthreads();
      }
      // ---- off-path: R0/R1 for next step ----
      gemv_half<32>(WH0, sm.c.h0, 256, sm.c.part, tid);
      __syncthreads();
      if (tid < 512) sm.c.r0res[tid] = f4add(sm.c.part[tid], sm.c.part[512 + tid]);
      __syncthreads();
      gemv_half<32>(WH1, sm.c.h1, 256, sm.c.part, tid);
      __syncthreads();
      if (tid < 512) sm.c.r1res[tid] = f4add(sm.c.part[tid], sm.c.part[512 + tid]);
      __syncthreads();
      // ---- D-completion mirror ----
      if (tid < 64) {
        unsigned v = T;
        for (;;) {
          if (tid < 7) v = ld_cohu(flags + FL_DFLAG + (blk * 7 + tid) * FSTR);
          if (__all((int)(v >= T))) break;
          __builtin_amdgcn_s_sleep(4);
        }
      }
      __syncthreads();
      if (tid == 0) st_cohu(flags + FL_DMIR + blk * FSTR, T);
      if (tid < 64) {
        unsigned v = T;
        for (;;) {
          if (tid < 32) v = ld_cohu(flags + FL_DMIR + tid * FSTR);
          if (__all((int)(v >= T))) break;
          __builtin_amdgcn_s_sleep(2);
        }
      }
      __syncthreads();
      // ---- argmax fold for own 4 batches ----
      {
        int bb = tid >> 8, i = tid & 255;
        unsigned long long k = ld_coh64(key2 + (size_t)(bg * 4 + bb) * 256 + i);
        k = wmax64(k);
        if ((tid & 63) == 0) sm.c.fred[tid >> 6] = k;
      }
      __syncthreads();
      if (tid < 4) {
        int bb = tid;
        unsigned long long m = u64max(u64max(sm.c.fred[bb * 4], sm.c.fred[bb * 4 + 1]),
                                      u64max(sm.c.fred[bb * 4 + 2], sm.c.fred[bb * 4 + 3]));
        int v = (int)(~(unsigned)m);
        int outv = sm.c.alldone ? 0 : v;
        out[(bg * 4 + bb) * TSTEPS + t] = outv;
        int nd = ((sm.c.done4 >> bb) & 1) | (outv == eos ? 1 : 0);
        sm.c.tok[bb] = outv;
        sm.c.fm[bb] = (unsigned)nd;
      }
      __syncthreads();
      if (tid == 0) {
        int mask = (int)(sm.c.fm[0] | (sm.c.fm[1] << 1) | (sm.c.fm[2] << 2) | (sm.c.fm[3] << 3));
        sm.c.done4 = mask;
        if (t < TSTEPS - 1)
          st_cohu(flags + FL_TOK + blk * FSTR, ((unsigned)(t + 1) << 8) | (unsigned)mask);
      }
      __syncthreads();
    }
  } else {
    // ======================= D (logits) block =======================
    // Tile: thread = (v = tid&31 row-slot, bp = tid>>5 batch-pair).
    // Rows {v, 32+v, 64+v, 96+v} + epi row 128+v (v<nep); batches {2bp, 2bp+1}.
    // Per wave per k4: 4 half-wide w + 1 masked epi-w + 2 paired h = 7 LDS
    // issues (vs 11 before). Key fold: 5-step half-wave shuffle (vs 48 issues).
    const int d = blk - NCELL;
    const int r0 = (d * 32000) / ND, r1 = ((d + 1) * 32000) / ND;
    const int rows = r1 - r0, nep = rows - 128;  // 14 or 15
    const int v = tid & 31, bp = tid >> 5;
    const float4* Wout4 = (const float4*)Wout;
    const int nq = 144 * 16;

    float bbm[4];
#pragma unroll
    for (int rs = 0; rs < 4; ++rs) bbm[rs] = bout[r0 + rs * 32 + v];
    const float bbE = (v < nep) ? bout[r0 + 128 + v] : 0.f;

    for (int t = 0; t < TSTEPS; ++t) {
      const unsigned T = (unsigned)(t + 1);
      // prefetch kc=0 Wout chunk (token-independent)
      float4 wpre[3];
#pragma unroll
      for (int p = 0; p < 3; ++p) {
        int e = tid + p * 1024;
        if (e < nq) {
          int j = e / 144, r = e - j * 144;
          int rc = r0 + r; if (rc > 31999) rc = 31999;
          wpre[p] = ldnt_f4(Wout4 + (size_t)rc * 64 + j);
        } else wpre[p] = make_float4(0.f, 0.f, 0.f, 0.f);
      }
      // EARLY-STAGE kc0 w into LDS (token-independent; prior step's end-barrier
      // ordered all reads of sm.d.w before this write) — overlaps the h1 wait.
#pragma unroll
      for (int p = 0; p < 3; ++p) {
        int e = tid + p * 1024;
        if (e < nq) {
          int j = e / 144, r = e - j * 144;
          *(float4*)&sm.d.w[(j * 144 + r) * 4] = wpre[p];
        }
      }
      // wait h1 ready: wave0 polls all 32 H1C flags directly (no cell relay)
      if (tid < 64) {
        unsigned hv = T;
        for (;;) {
          if (tid < 32) hv = ld_cohu(flags + FL_H1C + tid * FSTR);
          if (__all((int)(hv >= T))) break;
          __builtin_amdgcn_s_sleep(4);
        }
      }
      __syncthreads();
      // read full h1 into registers (4 x 16B batched coherent loads)
      float4 hpre[4];
      {
        int b = tid >> 4, j = tid & 15;
        const float4* hp = (const float4*)h1b4 + (size_t)b * 64 + j;
        ldg_coh_f4x4(hp, hp + 16, hp + 32, hp + 48, hpre[0], hpre[1], hpre[2], hpre[3]);
      }
      float accA[4], accB[4];
      float eaA = 0.f, eaB = 0.f;
#pragma unroll
      for (int i = 0; i < 4; ++i) { accA[i] = 0.f; accB[i] = 0.f; }

      // kc loop MUST stay fully unrolled: hpre[kc] must be statically indexed
      // (rolled loop -> scratch; that was R4's 2.3GB WRITE_SIZE regression).
#pragma unroll
      for (int kc = 0; kc < 4; ++kc) {
        if (kc > 0) {
          __syncthreads();
#pragma unroll
          for (int p = 0; p < 3; ++p) {
            int e = tid + p * 1024;
            if (e < nq) {
              int j = e / 144, r = e - j * 144;
              *(float4*)&sm.d.w[(j * 144 + r) * 4] = wpre[p];
            }
          }
        }
        {
          int b = tid >> 4, j = tid & 15;
          *(float4*)&sm.d.h[b * 68 + j * 4] = hpre[kc];
        }
        __syncthreads();
        if (kc < 3) {
#pragma unroll
          for (int p = 0; p < 3; ++p) {
            int e = tid + p * 1024;
            if (e < nq) {
              int j = e / 144, r = e - j * 144;
              int rc = r0 + r; if (rc > 31999) rc = 31999;
              wpre[p] = ldnt_f4(Wout4 + (size_t)rc * 64 + (kc + 1) * 16 + j);
            }
          }
        }
        // main: 4 rows x 2 batches (+ epi row x 2 batches)
#pragma unroll 4
        for (int k4 = 0; k4 < 16; ++k4) {
          const float* wb = &sm.d.w[(k4 * 144) * 4];
          float4 w0 = *(const float4*)&wb[v * 4];
          float4 w1 = *(const float4*)&wb[(32 + v) * 4];
          float4 w2 = *(const float4*)&wb[(64 + v) * 4];
          float4 w3 = *(const float4*)&wb[(96 + v) * 4];
          float4 hA = *(const float4*)&sm.d.h[(2 * bp) * 68 + k4 * 4];
          float4 hB = *(const float4*)&sm.d.h[(2 * bp + 1) * 68 + k4 * 4];
          accA[0] = fmaf(w0.x, hA.x, fmaf(w0.y, hA.y, fmaf(w0.z, hA.z, fmaf(w0.w, hA.w, accA[0]))));
          accB[0] = fmaf(w0.x, hB.x, fmaf(w0.y, hB.y, fmaf(w0.z, hB.z, fmaf(w0.w, hB.w, accB[0]))));
          accA[1] = fmaf(w1.x, hA.x, fmaf(w1.y, hA.y, fmaf(w1.z, hA.z, fmaf(w1.w, hA.w, accA[1]))));
          accB[1] = fmaf(w1.x, hB.x, fmaf(w1.y, hB.y, fmaf(w1.z, hB.z, fmaf(w1.w, hB.w, accB[1]))));
          accA[2] = fmaf(w2.x, hA.x, fmaf(w2.y, hA.y, fmaf(w2.z, hA.z, fmaf(w2.w, hA.w, accA[2]))));
          accB[2] = fmaf(w2.x, hB.x, fmaf(w2.y, hB.y, fmaf(w2.z, hB.z, fmaf(w2.w, hB.w, accB[2]))));
          accA[3] = fmaf(w3.x, hA.x, fmaf(w3.y, hA.y, fmaf(w3.z, hA.z, fmaf(w3.w, hA.w, accA[3]))));
          accB[3] = fmaf(w3.x, hB.x, fmaf(w3.y, hB.y, fmaf(w3.z, hB.z, fmaf(w3.w, hB.w, accB[3]))));
          if (v < nep) {
            float4 wE = *(const float4*)&wb[(128 + v) * 4];
            eaA = fmaf(wE.x, hA.x, fmaf(wE.y, hA.y, fmaf(wE.z, hA.z, fmaf(wE.w, hA.w, eaA))));
            eaB = fmaf(wE.x, hB.x, fmaf(wE.y, hB.y, fmaf(wE.z, hB.z, fmaf(wE.w, hB.w, eaB))));
          }
        }
      }
      // ---- keys: per-thread fold over 4(+1) rows, then 5-step half-wave reduce ----
      unsigned long long kA = packkey(accA[0] + bbm[0], r0 + v);
      kA = u64max(kA, packkey(accA[1] + bbm[1], r0 + 32 + v));
      kA = u64max(kA, packkey(accA[2] + bbm[2], r0 + 64 + v));
      kA = u64max(kA, packkey(accA[3] + bbm[3], r0 + 96 + v));
      unsigned long long kB = packkey(accB[0] + bbm[0], r0 + v);
      kB = u64max(kB, packkey(accB[1] + bbm[1], r0 + 32 + v));
      kB = u64max(kB, packkey(accB[2] + bbm[2], r0 + 64 + v));
      kB = u64max(kB, packkey(accB[3] + bbm[3], r0 + 96 + v));
      if (v < nep) {
        kA = u64max(kA, packkey(eaA + bbE, r0 + 128 + v));
        kB = u64max(kB, packkey(eaB + bbE, r0 + 128 + v));
      }
      // offsets 1..16: lanes stay within their 32-lane half (no batch mixing)
#pragma unroll
      for (int off = 1; off < 32; off <<= 1) {
        kA = u64max(kA, __shfl_xor(kA, off, 64));
        kB = u64max(kB, __shfl_xor(kB, off, 64));
      }
      if ((tid & 31) == 0) {
        sm.d.kr[2 * bp] = kA;
        sm.d.kr[2 * bp + 1] = kB;
      }
      __syncthreads();
      if (tid < 64) st_coh64(key2 + (size_t)tid * 256 + d, sm.d.kr[tid]);
      drain_vm();
      __syncthreads();
      if (tid == 0) st_cohu(flags + FL_DFLAG + d * FSTR, T);
    }
  }
}

extern "C" void kernel_launch(void* const* d_in, const int* in_sizes, int n_in,
                              void* d_out, int out_size, void* d_ws, size_t ws_size,
                              hipStream_t stream) {
  const float* enc  = (const float*)d_in[0];
  const float* emb  = (const float*)d_in[1];
  const float* Wh   = (const float*)d_in[2];
  const float* bh   = (const float*)d_in[3];
  const float* Wc   = (const float*)d_in[4];
  const float* bc   = (const float*)d_in[5];
  const float* Wih0 = (const float*)d_in[6];
  const float* Whh0 = (const float*)d_in[7];
  const float* bih0 = (const float*)d_in[8];
  const float* bhh0 = (const float*)d_in[9];
  const float* Wih1 = (const float*)d_in[10];
  const float* Whh1 = (const float*)d_in[11];
  const float* bih1 = (const float*)d_in[12];
  const float* bhh1 = (const float*)d_in[13];
  const float* Wout = (const float*)d_in[14];
  const float* bout = (const float*)d_in[15];
  const int* sosp   = (const int*)d_in[16];
  const int* eosp   = (const int*)d_in[17];

  float* ws = (float*)d_ws;
  char* base = (char*)d_ws + (size_t)OFF_FLOAT_END * 4;
  unsigned long long* key2 = (unsigned long long*)base;            // 131072 B
  unsigned* flags          = (unsigned*)(base + 131072);           // 49152 B
  int* out = (int*)d_out;

  lstm_init_kernel<<<80, 256, 0, stream>>>(enc, Wh, bh, Wc, bc, bih0, bhh0,
                                           bih1, bhh1, ws, key2, flags);
  lstm_relayout_kernel<<<256, 256, 0, stream>>>(Wih0, Whh0, Wih1, Whh1, ws);
  lstm_decode_kernel<<<NBLK, 1024, 0, stream>>>(emb, Wout, bout, sosp, eosp,
                                                ws, key2, flags, out);
}

// Round 8
// 3327.958 us; speedup vs baseline: 1.4507x; 1.4484x over previous
//
#include <hip/hip_runtime.h>
#include <math.h>

#define TSTEPS 48
#define NCELL 32
#define ND 224
#define NBLK (NCELL + ND)

// ---------------- ws float offsets ----------------
#define OFF_W0T   0            // [2 hh][128 k4][512 gc] float4 (Wih0 re-layout)
#define OFF_W1T   524288       // [2][64][512] float4 (Wih1)
#define OFF_WH0T  786432       // [2][64][512] float4 (Whh0)
#define OFF_WH1T  1048576      // [2][64][512] float4 (Whh1)
#define OFF_BS0   1310720      // [2 hh][512 gc]
#define OFF_BS1   1311744
#define OFF_HINIT 1312768      // [64][256]
#define OFF_CINIT 1329152
#define OFF_H0BUF 1345536      // [64][256]
#define OFF_H1BUF 1361920
#define OFF_FLOAT_END 1378304
// then: key2 u64[64][256] (131072 B), flags u32[12288] (49152 B)

#define FSTR 32
#define FL_H0F   0       // 32
#define FL_H1C   1024    // 32
#define FL_H1ALL 2048    // 32 (unused: D polls H1C directly)
#define FL_DFLAG 3072    // 224
#define FL_DMIR  10240   // 32
#define FL_TOK   11264   // 32
#define NFLAGU32 12288

// ---- dynamic smem layout for D blocks (bytes) ----
// w  : [16 k4][144 rows] float4      at 0          (36864 B)
// h  : [64 b][65 f4] (full h1, padded row = 1040 B) at 36864 (66560 B)
// kr : 64 u64                        at 103424     (512 B)
#define DOFF_H   36864
#define DOFF_KR  103424
#define DYN_SMEM 103936

typedef float f4v __attribute__((ext_vector_type(4)));

// ---- coherent accessors ----
__device__ __forceinline__ unsigned ld_cohu(const unsigned* p) {
  return __hip_atomic_load((unsigned*)p, __ATOMIC_RELAXED, __HIP_MEMORY_SCOPE_AGENT);
}
__device__ __forceinline__ void st_cohu(unsigned* p, unsigned v) {
  __hip_atomic_store(p, v, __ATOMIC_RELAXED, __HIP_MEMORY_SCOPE_AGENT);
}
__device__ __forceinline__ unsigned long long ld_coh64(const unsigned long long* p) {
  return __hip_atomic_load((unsigned long long*)p, __ATOMIC_RELAXED, __HIP_MEMORY_SCOPE_AGENT);
}
__device__ __forceinline__ void st_coh64(unsigned long long* p, unsigned long long v) {
  __hip_atomic_store(p, v, __ATOMIC_RELAXED, __HIP_MEMORY_SCOPE_AGENT);
}
// 16B coherent load (bypass L0+L2 -> IC), blocking
__device__ __forceinline__ float4 ldg_coh_f4(const float4* p) {
  f4v r;
  asm volatile("global_load_dwordx4 %0, %1, off sc0 sc1\n\ts_waitcnt vmcnt(0)"
               : "=v"(r) : "v"(p) : "memory");
  return make_float4(r.x, r.y, r.z, r.w);
}
// 4 x 16B coherent loads in flight, one wait
__device__ __forceinline__ void ldg_coh_f4x4(const float4* p0, const float4* p1,
                                             const float4* p2, const float4* p3,
                                             float4& a, float4& b, float4& c, float4& d) {
  f4v ra, rb, rc, rd;
  asm volatile(
      "global_load_dwordx4 %0, %4, off sc0 sc1\n\t"
      "global_load_dwordx4 %1, %5, off sc0 sc1\n\t"
      "global_load_dwordx4 %2, %6, off sc0 sc1\n\t"
      "global_load_dwordx4 %3, %7, off sc0 sc1\n\t"
      "s_waitcnt vmcnt(0)"
      : "=&v"(ra), "=&v"(rb), "=&v"(rc), "=&v"(rd)
      : "v"(p0), "v"(p1), "v"(p2), "v"(p3) : "memory");
  a = make_float4(ra.x, ra.y, ra.z, ra.w);
  b = make_float4(rb.x, rb.y, rb.z, rb.w);
  c = make_float4(rc.x, rc.y, rc.z, rc.w);
  d = make_float4(rd.x, rd.y, rd.z, rd.w);
}
// 16B coherent write-through store (fire and forget; drain_vm before flag post)
__device__ __forceinline__ void stg_coh_f4(float4* p, float4 v) {
  f4v t = {v.x, v.y, v.z, v.w};
  asm volatile("global_store_dwordx4 %0, %1, off sc0 sc1" :: "v"(p), "v"(t) : "memory");
}
__device__ __forceinline__ void drain_vm() {
  asm volatile("s_waitcnt vmcnt(0)" ::: "memory");
}
// non-temporal 16B load (streaming; don't pollute L2 — protects cell weights in L2)
__device__ __forceinline__ float4 ldnt_f4(const float4* p) {
  f4v v = __builtin_nontemporal_load((const f4v*)p);
  return make_float4(v.x, v.y, v.z, v.w);
}
__device__ __forceinline__ float sigf(float x) { return 1.0f / (1.0f + expf(-x)); }
__device__ __forceinline__ unsigned long long u64max(unsigned long long a, unsigned long long b) {
  return a > b ? a : b;
}
__device__ __forceinline__ unsigned long long wmax64(unsigned long long k) {
#pragma unroll
  for (int off = 1; off < 64; off <<= 1) {
    unsigned long long o = __shfl_xor(k, off, 64);
    k = u64max(k, o);
  }
  return k;
}
__device__ __forceinline__ unsigned long long packkey(float lg, int v) {
  unsigned u = __float_as_uint(lg);
  u = (u & 0x80000000u) ? ~u : (u | 0x80000000u);
  return ((unsigned long long)u << 32) | (unsigned)(~(unsigned)v);
}
__device__ __forceinline__ float4 f4add(float4 a, float4 b) {
  return make_float4(a.x + b.x, a.y + b.y, a.z + b.z, a.w + b.w);
}
__device__ __forceinline__ float dot4(float4 w, float4 h, float acc) {
  return fmaf(w.x, h.x, fmaf(w.y, h.y, fmaf(w.z, h.z, fmaf(w.w, h.w, acc))));
}

// ---------------- init kernels ----------------
__global__ void lstm_init_kernel(const float* enc, const float* Wh, const float* bh,
                                 const float* Wc, const float* bc,
                                 const float* bih0, const float* bhh0,
                                 const float* bih1, const float* bhh1,
                                 float* ws, unsigned long long* key2, unsigned* flags) {
  const int tid = threadIdx.x, blk = blockIdx.x;
  if (blk < 64) {
    __shared__ float el[256];
    el[tid] = enc[blk * 256 + tid];
    __syncthreads();
    const float4* el4 = (const float4*)el;
    const float4* wh4 = (const float4*)(Wh + tid * 256);
    const float4* wc4 = (const float4*)(Wc + tid * 256);
    float ah = bh[tid], ac = bc[tid];
#pragma unroll 4
    for (int f = 0; f < 64; ++f) {
      float4 x = el4[f], a = wh4[f], b = wc4[f];
      ah = fmaf(a.x, x.x, fmaf(a.y, x.y, fmaf(a.z, x.z, fmaf(a.w, x.w, ah))));
      ac = fmaf(b.x, x.x, fmaf(b.y, x.y, fmaf(b.z, x.z, fmaf(b.w, x.w, ac))));
    }
    ws[OFF_HINIT + blk * 256 + tid] = ah;
    ws[OFF_CINIT + blk * 256 + tid] = ac;
  } else if (blk == 64) {
    for (int g = tid; g < 1024; g += 256) {
      int hh = g >> 9, gc = g & 511;
      int row = (gc >> 7) * 256 + hh * 128 + (gc & 127);
      ws[OFF_BS0 + g] = bih0[row] + bhh0[row];
      ws[OFF_BS1 + g] = bih1[row] + bhh1[row];
    }
  } else {
    const int base = (blk - 65) * 256 + tid;  // 15 blocks, stride 3840
    for (int i = base; i < 64 * 256; i += 15 * 256) key2[i] = 0ull;
    for (int i = base; i < NFLAGU32; i += 15 * 256) flags[i] = 0u;
  }
}

// re-layout the 4 gate-weight matrices into [hh][k4][512 gc] float4
__global__ void lstm_relayout_kernel(const float* Wih0, const float* Whh0,
                                     const float* Wih1, const float* Whh1, float* ws) {
  const int gid = blockIdx.x * 256 + threadIdx.x;
  const int gstr = 256 * 256;
  const float* srcs[4] = {Wih0, Wih1, Whh0, Whh1};
  const int dsts[4] = {OFF_W0T, OFF_W1T, OFF_WH0T, OFF_WH1T};
  const int k4tot[4] = {128, 64, 64, 64};
  for (int s = 0; s < 4; ++s) {
    const int n = 2 * k4tot[s] * 512;
    float4* dst = (float4*)(ws + dsts[s]);
    const float4* src = (const float4*)srcs[s];
    for (int e = gid; e < n; e += gstr) {
      int hh = e / (k4tot[s] * 512);
      int r = e - hh * k4tot[s] * 512;
      int k4 = r / 512, gc = r - k4 * 512;
      int row = (gc >> 7) * 256 + hh * 128 + (gc & 127);
      dst[e] = src[(size_t)row * k4tot[s] + k4];
    }
  }
}

// ---------------- decode: cell shared-memory layout ----------------
struct CellSm {
  float x[4 * 512];
  float4 part[1024];
  float4 r0res[512];
  float4 r1res[512];
  float h0[4 * 256];
  float h1[4 * 256];
  float c0[4 * 128];
  float c1[4 * 128];
  int tok[4];
  unsigned fm[32];
  unsigned long long fred[16];
  int done4;
  int alldone;
};

// GEMV half: thread (gc = tid&511, kh = tid>>9) accumulates its K-half for 4 batches.
template <int K4H>
__device__ __forceinline__ void gemv_half(const float4* __restrict__ W,
                                          const float* __restrict__ xl, int xstride,
                                          float4* __restrict__ part, int tid) {
  const int kh = tid >> 9;
  float a0 = 0.f, a1 = 0.f, a2 = 0.f, a3 = 0.f;
  const float4* wp = W + (size_t)(kh * K4H) * 512 + (tid & 511);
  const float* x0 = xl + kh * K4H * 4;
#pragma unroll 8
  for (int i = 0; i < K4H; ++i) {
    float4 w = wp[(size_t)i * 512];
    float4 xa = *(const float4*)(x0 + i * 4);
    float4 xb = *(const float4*)(x0 + xstride + i * 4);
    float4 xc = *(const float4*)(x0 + 2 * xstride + i * 4);
    float4 xd = *(const float4*)(x0 + 3 * xstride + i * 4);
    a0 = fmaf(w.x, xa.x, fmaf(w.y, xa.y, fmaf(w.z, xa.z, fmaf(w.w, xa.w, a0))));
    a1 = fmaf(w.x, xb.x, fmaf(w.y, xb.y, fmaf(w.z, xb.z, fmaf(w.w, xb.w, a1))));
    a2 = fmaf(w.x, xc.x, fmaf(w.y, xc.y, fmaf(w.z, xc.z, fmaf(w.w, xc.w, a2))));
    a3 = fmaf(w.x, xd.x, fmaf(w.y, xd.y, fmaf(w.z, xd.z, fmaf(w.w, xd.w, a3))));
  }
  part[tid] = make_float4(a0, a1, a2, a3);
}

__device__ __forceinline__ void cellfold(const float4* part, const float4* rres,
                                         const float* bs, float* cst, float* hst,
                                         int hh, int tid) {
  if (tid < 512) {
    int jj = tid & 127, b = tid >> 7;
    float g[4];
#pragma unroll
    for (int q = 0; q < 4; ++q) {
      int gc = q * 128 + jj;
      g[q] = ((const float*)&part[gc])[b] + ((const float*)&part[512 + gc])[b] +
             ((const float*)&rres[gc])[b] + bs[gc];
    }
    float c = cst[b * 128 + jj];
    float cn = sigf(g[1]) * c + sigf(g[0]) * tanhf(g[2]);
    float hn = sigf(g[3]) * tanhf(cn);
    cst[b * 128 + jj] = cn;
    hst[b * 256 + hh * 128 + jj] = hn;
  }
}

__global__ __launch_bounds__(1024, 4) void lstm_decode_kernel(
    const float* __restrict__ emb, const float* __restrict__ Wout,
    const float* __restrict__ bout, const int* __restrict__ sosp,
    const int* __restrict__ eosp, float* __restrict__ ws,
    unsigned long long* __restrict__ key2, unsigned* __restrict__ flags,
    int* __restrict__ out) {
  const int tid = threadIdx.x;
  const int blk = blockIdx.x;
  extern __shared__ char dynsm[];
  const int eos = *eosp;
  const int sos = *sosp;
  float4* h0b4 = (float4*)(ws + OFF_H0BUF);
  float4* h1b4 = (float4*)(ws + OFF_H1BUF);

  if (blk < NCELL) {
    // ======================= CELL block =======================
    CellSm& cs = *(CellSm*)dynsm;
    const int bg = blk >> 1, hh = blk & 1, ph = 1 - hh;
    const float4* W0 = (const float4*)(ws + OFF_W0T) + (size_t)hh * 128 * 512;
    const float4* W1 = (const float4*)(ws + OFF_W1T) + (size_t)hh * 64 * 512;
    const float4* WH0 = (const float4*)(ws + OFF_WH0T) + (size_t)hh * 64 * 512;
    const float4* WH1 = (const float4*)(ws + OFF_WH1T) + (size_t)hh * 64 * 512;
    const float* bs0 = ws + OFF_BS0 + hh * 512;
    const float* bs1 = ws + OFF_BS1 + hh * 512;

    // t=0 state seed
    {
      int b = tid >> 8, k = tid & 255;
      float hv = ws[OFF_HINIT + (bg * 4 + b) * 256 + k];
      cs.h0[b * 256 + k] = hv;
      cs.h1[b * 256 + k] = hv;
    }
    if (tid < 512) {
      int b = tid >> 7, jj = tid & 127;
      float cv = ws[OFF_CINIT + (bg * 4 + b) * 256 + hh * 128 + jj];
      cs.c0[b * 128 + jj] = cv;
      cs.c1[b * 128 + jj] = cv;
    }
    if (tid < 4) cs.tok[tid] = sos;
    if (tid == 0) { cs.done4 = 0; cs.alldone = 0; }
    __syncthreads();
    // seed R0res/R1res from init states
    gemv_half<32>(WH0, cs.h0, 256, cs.part, tid);
    __syncthreads();
    if (tid < 512) cs.r0res[tid] = f4add(cs.part[tid], cs.part[512 + tid]);
    __syncthreads();
    gemv_half<32>(WH1, cs.h1, 256, cs.part, tid);
    __syncthreads();
    if (tid < 512) cs.r1res[tid] = f4add(cs.part[tid], cs.part[512 + tid]);
    __syncthreads();

    for (int t = 0; t < TSTEPS; ++t) {
      const unsigned T = (unsigned)(t + 1);
      // ---- E = Wih0(half) @ emb[tok] ----
      if (tid < 512) {
        int b = tid >> 7, j = tid & 127;
        ((float4*)cs.x)[b * 128 + j] = ((const float4*)emb)[(size_t)cs.tok[b] * 128 + j];
      }
      __syncthreads();
      gemv_half<64>(W0, cs.x, 512, cs.part, tid);
      __syncthreads();
      cellfold(cs.part, cs.r0res, bs0, cs.c0, cs.h0, hh, tid);
      __syncthreads();
      // post own h0 half, exchange with partner
      if (tid < 128) {
        int b = tid >> 5, j = tid & 31;
        float4 v = *(float4*)&cs.h0[b * 256 + hh * 128 + j * 4];
        stg_coh_f4(h0b4 + (bg * 4 + b) * 64 + hh * 32 + j, v);
      }
      drain_vm();
      __syncthreads();
      if (tid == 0) {
        st_cohu(flags + FL_H0F + blk * FSTR, T);
        while (ld_cohu(flags + FL_H0F + (blk ^ 1) * FSTR) < T) __builtin_amdgcn_s_sleep(1);
      }
      __syncthreads();
      if (tid < 128) {
        int b = tid >> 5, j = tid & 31;
        float4 v = ldg_coh_f4(h0b4 + (bg * 4 + b) * 64 + ph * 32 + j);
        *(float4*)&cs.h0[b * 256 + ph * 128 + j * 4] = v;
      }
      __syncthreads();
      // ---- G1 = Wih1(half) @ h0 ----
      gemv_half<32>(W1, cs.h0, 256, cs.part, tid);
      __syncthreads();
      cellfold(cs.part, cs.r1res, bs1, cs.c1, cs.h1, hh, tid);
      __syncthreads();
      // post h1 half + flag; D blocks observe the 32 H1C flags directly.
      if (tid < 128) {
        int b = tid >> 5, j = tid & 31;
        float4 v = *(float4*)&cs.h1[b * 256 + hh * 128 + j * 4];
        stg_coh_f4(h1b4 + (bg * 4 + b) * 64 + hh * 32 + j, v);
      }
      drain_vm();
      __syncthreads();
      if (tid == 0) {
        st_cohu(flags + FL_H1C + blk * FSTR, T);
        while (ld_cohu(flags + FL_H1C + (blk ^ 1) * FSTR) < T) __builtin_amdgcn_s_sleep(1);
      }
      __syncthreads();
      // read partner h1 half (for R1)
      if (tid < 128) {
        int b = tid >> 5, j = tid & 31;
        float4 v = ldg_coh_f4(h1b4 + (bg * 4 + b) * 64 + ph * 32 + j);
        *(float4*)&cs.h1[b * 256 + ph * 128 + j * 4] = v;
      }
      __syncthreads();
      // ---- off-path: masks from step t-1 (for alldone) ----
      if (t > 0) {
        if (tid < 64) {
          unsigned tgt = (unsigned)t << 8;
          unsigned got = tgt;
          for (;;) {
            if (tid < 32) got = ld_cohu(flags + FL_TOK + tid * FSTR);
            if (__all((int)(got >= tgt))) break;
            __builtin_amdgcn_s_sleep(2);
          }
          if (tid < 32) cs.fm[tid] = got & 0xFFu;
        }
        __syncthreads();
        if (tid < 64) {
          int ok = 1;
          if (tid < 32) ok = (cs.fm[tid] == 0xFu);
          int all = __all(ok);
          if (tid == 0) cs.alldone = all;
        }
        __syncthreads();
      }
      // ---- off-path: R0/R1 for next step ----
      gemv_half<32>(WH0, cs.h0, 256, cs.part, tid);
      __syncthreads();
      if (tid < 512) cs.r0res[tid] = f4add(cs.part[tid], cs.part[512 + tid]);
      __syncthreads();
      gemv_half<32>(WH1, cs.h1, 256, cs.part, tid);
      __syncthreads();
      if (tid < 512) cs.r1res[tid] = f4add(cs.part[tid], cs.part[512 + tid]);
      __syncthreads();
      // ---- D-completion mirror ----
      if (tid < 64) {
        unsigned v = T;
        for (;;) {
          if (tid < 7) v = ld_cohu(flags + FL_DFLAG + (blk * 7 + tid) * FSTR);
          if (__all((int)(v >= T))) break;
          __builtin_amdgcn_s_sleep(4);
        }
      }
      __syncthreads();
      if (tid == 0) st_cohu(flags + FL_DMIR + blk * FSTR, T);
      if (tid < 64) {
        unsigned v = T;
        for (;;) {
          if (tid < 32) v = ld_cohu(flags + FL_DMIR + tid * FSTR);
          if (__all((int)(v >= T))) break;
          __builtin_amdgcn_s_sleep(2);
        }
      }
      __syncthreads();
      // ---- argmax fold for own 4 batches ----
      {
        int bb = tid >> 8, i = tid & 255;
        unsigned long long k = ld_coh64(key2 + (size_t)(bg * 4 + bb) * 256 + i);
        k = wmax64(k);
        if ((tid & 63) == 0) cs.fred[tid >> 6] = k;
      }
      __syncthreads();
      if (tid < 4) {
        int bb = tid;
        unsigned long long m = u64max(u64max(cs.fred[bb * 4], cs.fred[bb * 4 + 1]),
                                      u64max(cs.fred[bb * 4 + 2], cs.fred[bb * 4 + 3]));
        int v = (int)(~(unsigned)m);
        int outv = cs.alldone ? 0 : v;
        out[(bg * 4 + bb) * TSTEPS + t] = outv;
        int nd = ((cs.done4 >> bb) & 1) | (outv == eos ? 1 : 0);
        cs.tok[bb] = outv;
        cs.fm[bb] = (unsigned)nd;
      }
      __syncthreads();
      if (tid == 0) {
        int mask = (int)(cs.fm[0] | (cs.fm[1] << 1) | (cs.fm[2] << 2) | (cs.fm[3] << 3));
        cs.done4 = mask;
        if (t < TSTEPS - 1)
          st_cohu(flags + FL_TOK + blk * FSTR, ((unsigned)(t + 1) << 8) | (unsigned)mask);
      }
      __syncthreads();
    }
  } else {
    // ======================= D (logits) block =======================
    // Tile: thread = (v = tid&31 row-slot, bp = tid>>5 batch-pair).
    // Rows {v, 32+v, 64+v, 96+v} + epi row 128+v (v<nep); batches {2bp, 2bp+1}.
    // Full h1 lives in LDS (staged once/step) -> no hpre[4] held across the
    // kc pipeline (r4/r6 spilled exactly that). Per wave per k4: 4 wide w +
    // 1 epi w + 2 half-bcast h = 7 LDS issues vs r0's ~13 equivalent.
    const int d = blk - NCELL;
    const int r0 = (d * 32000) / ND, r1 = ((d + 1) * 32000) / ND;
    const int rows = r1 - r0, nep = rows - 128;  // 14 or 15
    const int v = tid & 31, bp = tid >> 5;
    float4* wsm = (float4*)dynsm;                 // [16][144] f4
    float4* hl  = (float4*)(dynsm + DOFF_H);      // [64][65] f4
    unsigned long long* kr = (unsigned long long*)(dynsm + DOFF_KR);
    const float4* Wout4 = (const float4*)Wout;
    const int nq = 144 * 16;

    float bbm[4];
#pragma unroll
    for (int rs = 0; rs < 4; ++rs) bbm[rs] = bout[r0 + rs * 32 + v];
    const float bbE = (v < nep) ? bout[r0 + 128 + v] : 0.f;

    for (int t = 0; t < TSTEPS; ++t) {
      const unsigned T = (unsigned)(t + 1);
      // prefetch + early-stage kc0 Wout chunk (token-independent; prior
      // step's end barrier ordered all reads of wsm) — overlaps the h1 wait.
      {
        float4 wpre[3];
#pragma unroll
        for (int p = 0; p < 3; ++p) {
          int e = tid + p * 1024;
          if (e < nq) {
            int j = e / 144, r = e - j * 144;
            int rc = r0 + r; if (rc > 31999) rc = 31999;
            wpre[p] = ldnt_f4(Wout4 + (size_t)rc * 64 + j);
          }
        }
#pragma unroll
        for (int p = 0; p < 3; ++p) {
          int e = tid + p * 1024;
          if (e < nq) {
            int j = e / 144, r = e - j * 144;
            wsm[j * 144 + r] = wpre[p];
          }
        }
      }
      // wait h1 ready: wave0 polls all 32 H1C flags directly
      if (tid < 64) {
        unsigned hv = T;
        for (;;) {
          if (tid < 32) hv = ld_cohu(flags + FL_H1C + tid * FSTR);
          if (__all((int)(hv >= T))) break;
          __builtin_amdgcn_s_sleep(4);
        }
      }
      __syncthreads();
      // stage FULL h1 -> LDS (transient registers only)
      {
        int b = tid >> 4, j = tid & 15;
        const float4* hp = h1b4 + (size_t)b * 64 + j;
        float4 ha, hb, hc, hd;
        ldg_coh_f4x4(hp, hp + 16, hp + 32, hp + 48, ha, hb, hc, hd);
        float4* hr = hl + b * 65;
        hr[j] = ha; hr[j + 16] = hb; hr[j + 32] = hc; hr[j + 48] = hd;
      }
      __syncthreads();

      float accA[4], accB[4];
      float eaA = 0.f, eaB = 0.f;
#pragma unroll
      for (int i = 0; i < 4; ++i) { accA[i] = 0.f; accB[i] = 0.f; }
      const float4* hlA = hl + (2 * bp) * 65;
      const float4* hlB = hlA + 65;

#pragma unroll
      for (int kc = 0; kc < 4; ++kc) {
        float4 wpre[3];
        if (kc < 3) {
#pragma unroll
          for (int p = 0; p < 3; ++p) {
            int e = tid + p * 1024;
            if (e < nq) {
              int j = e / 144, r = e - j * 144;
              int rc = r0 + r; if (rc > 31999) rc = 31999;
              wpre[p] = ldnt_f4(Wout4 + (size_t)rc * 64 + (kc + 1) * 16 + j);
            }
          }
        }
        // compute this chunk: 4 rows x 2 batches (+ epi), row-sequential
#pragma unroll 2
        for (int k4 = 0; k4 < 16; ++k4) {
          const float4* wb = wsm + k4 * 144;
          float4 hA = hlA[kc * 16 + k4];
          float4 hB = hlB[kc * 16 + k4];
#pragma unroll
          for (int rs = 0; rs < 4; ++rs) {
            float4 wr = wb[rs * 32 + v];
            accA[rs] = dot4(wr, hA, accA[rs]);
            accB[rs] = dot4(wr, hB, accB[rs]);
          }
          if (v < nep) {
            float4 wE = wb[128 + v];
            eaA = dot4(wE, hA, eaA);
            eaB = dot4(wE, hB, eaB);
          }
        }
        if (kc < 3) {
          __syncthreads();  // all reads of wsm done
#pragma unroll
          for (int p = 0; p < 3; ++p) {
            int e = tid + p * 1024;
            if (e < nq) {
              int j = e / 144, r = e - j * 144;
              wsm[j * 144 + r] = wpre[p];
            }
          }
          __syncthreads();  // next chunk visible
        }
      }
      // ---- keys: per-thread fold over 4(+1) rows, then 5-step half-wave reduce ----
      unsigned long long kA = packkey(accA[0] + bbm[0], r0 + v);
      kA = u64max(kA, packkey(accA[1] + bbm[1], r0 + 32 + v));
      kA = u64max(kA, packkey(accA[2] + bbm[2], r0 + 64 + v));
      kA = u64max(kA, packkey(accA[3] + bbm[3], r0 + 96 + v));
      unsigned long long kB = packkey(accB[0] + bbm[0], r0 + v);
      kB = u64max(kB, packkey(accB[1] + bbm[1], r0 + 32 + v));
      kB = u64max(kB, packkey(accB[2] + bbm[2], r0 + 64 + v));
      kB = u64max(kB, packkey(accB[3] + bbm[3], r0 + 96 + v));
      if (v < nep) {
        kA = u64max(kA, packkey(eaA + bbE, r0 + 128 + v));
        kB = u64max(kB, packkey(eaB + bbE, r0 + 128 + v));
      }
      // offsets 1..16: lanes stay within their 32-lane half (no batch mixing)
#pragma unroll
      for (int off = 1; off < 32; off <<= 1) {
        kA = u64max(kA, __shfl_xor(kA, off, 64));
        kB = u64max(kB, __shfl_xor(kB, off, 64));
      }
      if ((tid & 31) == 0) {
        kr[2 * bp] = kA;
        kr[2 * bp + 1] = kB;
      }
      __syncthreads();
      if (tid < 64) st_coh64(key2 + (size_t)tid * 256 + d, kr[tid]);
      drain_vm();
      __syncthreads();
      if (tid == 0) st_cohu(flags + FL_DFLAG + d * FSTR, T);
    }
  }
}

extern "C" void kernel_launch(void* const* d_in, const int* in_sizes, int n_in,
                              void* d_out, int out_size, void* d_ws, size_t ws_size,
                              hipStream_t stream) {
  const float* enc  = (const float*)d_in[0];
  const float* emb  = (const float*)d_in[1];
  const float* Wh   = (const float*)d_in[2];
  const float* bh   = (const float*)d_in[3];
  const float* Wc   = (const float*)d_in[4];
  const float* bc   = (const float*)d_in[5];
  const float* Wih0 = (const float*)d_in[6];
  const float* Whh0 = (const float*)d_in[7];
  const float* bih0 = (const float*)d_in[8];
  const float* bhh0 = (const float*)d_in[9];
  const float* Wih1 = (const float*)d_in[10];
  const float* Whh1 = (const float*)d_in[11];
  const float* bih1 = (const float*)d_in[12];
  const float* bhh1 = (const float*)d_in[13];
  const float* Wout = (const float*)d_in[14];
  const float* bout = (const float*)d_in[15];
  const int* sosp   = (const int*)d_in[16];
  const int* eosp   = (const int*)d_in[17];

  float* ws = (float*)d_ws;
  char* base = (char*)d_ws + (size_t)OFF_FLOAT_END * 4;
  unsigned long long* key2 = (unsigned long long*)base;            // 131072 B
  unsigned* flags          = (unsigned*)(base + 131072);           // 49152 B
  int* out = (int*)d_out;

  // opt-in to >64KB dynamic LDS (gfx950: 160 KB/CU)
  static int attr_done = 0;
  if (!attr_done) {
    (void)hipFuncSetAttribute((const void*)lstm_decode_kernel,
                              hipFuncAttributeMaxDynamicSharedMemorySize, DYN_SMEM);
    attr_done = 1;
  }

  lstm_init_kernel<<<80, 256, 0, stream>>>(enc, Wh, bh, Wc, bc, bih0, bhh0,
                                           bih1, bhh1, ws, key2, flags);
  lstm_relayout_kernel<<<256, 256, 0, stream>>>(Wih0, Whh0, Wih1, Whh1, ws);
  lstm_decode_kernel<<<NBLK, 1024, DYN_SMEM, stream>>>(emb, Wout, bout, sosp, eosp,
                                                       ws, key2, flags, out);
}